// Round 6
// baseline (597.705 us; speedup 1.0000x reference)
//
#include <hip/hip_runtime.h>
#include <hip/hip_bf16.h>
#include <cmath>

#define NDIM  64
#define PSTR  72        // LDS plane row stride in f16 (144 B, 16B-aligned rows)
#define NDEG  19        // Chebyshev degree for log on [0.75, 8.75]; trunc err ~1.3e-6
#define TRI   2080      // 64*65/2
#define CMID  4.75f     // interval midpoint m; h = 4

struct Coeffs {
    float c[NDEG + 1];  // c'_k = sigma_k * c_k  (sigma = +,+,-,-,+,+,...)
};

typedef _Float16 f16x8 __attribute__((ext_vector_type(8)));
typedef _Float16 f16x4 __attribute__((ext_vector_type(4)));
typedef float    f32x4 __attribute__((ext_vector_type(4)));

// SPD => symmetric under the TRUE dtype; wrong reinterpretation gives O(1)/NaN residual.
__device__ __forceinline__ bool sniff_is_bf16(const void* xin)
{
    const float*          f0 = (const float*)xin;
    const unsigned short* h0 = (const unsigned short*)xin;
    const int pi[8] = {1, 3, 5, 2, 4, 6, 7, 8};
    const int pj[8] = {2, 7, 11, 9, 13, 17, 23, 31};
    float fsym = 0.f, bsym = 0.f;
    #pragma unroll
    for (int p = 0; p < 8; ++p) {
        const int i = pi[p], j = pj[p];
        fsym += fabsf(f0[i * NDIM + j] - f0[j * NDIM + i]);
        union { unsigned u; float f; } ua, ub;
        ua.u = ((unsigned)h0[i * NDIM + j]) << 16;
        ub.u = ((unsigned)h0[j * NDIM + i]) << 16;
        bsym += fabsf(ua.f - ub.f);
    }
    if (fsym != fsym) return true;
    if (bsym != bsym) return false;
    return bsym < fsym;
}

// One 64x64 matrix per 256-thread block (4 waves). COLUMN-STRIP decomposition:
// wave w owns cols n0 = 16w..16w+15, ALL 64 rows, as 4 stacked 16x16 C/D tiles
// (tile mt = rows 16mt..16mt+15). The recurrence
//   T_{k+1}[:, strip] = A2 * T_k[:, strip] - T_{k-1}[:, strip],  A2 = (X - mI)/2
// is closed per wave, so the 17-step loop has ZERO barriers: the B-operand for
// step k is rebuilt from the wave's OWN C/D registers via a wave-private LDS
// scratch (4 ds_write_b64 + lgkmcnt(0) + 2 ds_read_b128 per step; within-wave
// write->read through LDS needs no s_barrier).
//
// Sign algebra (verified in the round-5 kernel): V_k = sigma_k T_k with sigma
// period 4 (+,+,-,-) makes every step a single in-place set = mfma(A2, frag, set)
// with C-in = V_{k-2}, frag = f16((k even ? - : +) * V_{k-1}); coefficients
// c'_k = sigma_k c_k are host-folded. A2 and T1 = A2/2 are EXACT in f16 for
// bf16 input (diagonal grid argument; exponent shifts).
//
// Scratch layout (per wave, 2048 B in the p1 region): data of C/D tile mt,
// writer lane (quad, l) = packed f16x4 {reg0..reg3} at f16-offset
//   WA = 1024*wave + 256*mt + 128*(quad>>1) + 8*(l ^ (4*(mt&1)+2*(quad>>1))) + 4*(quad&1)
// reader lane (q, l), frag kt reads b128 at
//   RA = 1024*wave + 256*(2kt+(q>>1)) + 128*(q&1) + 8*(l ^ 2q)
// (XOR block swizzle spreads banks; WA/RA consistency: reader q = 2*(mt&1)+(quad>>1),
// and 4*(q>>1)+2*(q&1) = 2q.)
//
// Scratch discipline (rule #20): all persistent state individually named, all
// vector subscripts literal, no pragma-loops inside macros.

#define XCHG_STEP(S0, S1, S2, S3, D0, D1, D2, D3, CK, SGN)                        \
    {                                                                             \
        f16x4 w0_, w1_, w2_, w3_;                                                 \
        w0_[0]=(_Float16)(SGN S0[0]); w0_[1]=(_Float16)(SGN S0[1]);               \
        w0_[2]=(_Float16)(SGN S0[2]); w0_[3]=(_Float16)(SGN S0[3]);               \
        w1_[0]=(_Float16)(SGN S1[0]); w1_[1]=(_Float16)(SGN S1[1]);               \
        w1_[2]=(_Float16)(SGN S1[2]); w1_[3]=(_Float16)(SGN S1[3]);               \
        w2_[0]=(_Float16)(SGN S2[0]); w2_[1]=(_Float16)(SGN S2[1]);               \
        w2_[2]=(_Float16)(SGN S2[2]); w2_[3]=(_Float16)(SGN S2[3]);               \
        w3_[0]=(_Float16)(SGN S3[0]); w3_[1]=(_Float16)(SGN S3[1]);               \
        w3_[2]=(_Float16)(SGN S3[2]); w3_[3]=(_Float16)(SGN S3[3]);               \
        *(f16x4*)&p1[wa0] = w0_;  *(f16x4*)&p1[wa1] = w1_;                        \
        *(f16x4*)&p1[wa2] = w2_;  *(f16x4*)&p1[wa3] = w3_;                        \
        asm volatile("s_waitcnt lgkmcnt(0)" ::: "memory");                        \
        const f16x8 bf0_ = *(const f16x8*)&p1[ra0];                               \
        const f16x8 bf1_ = *(const f16x8*)&p1[ra1];                               \
        D0 = __builtin_amdgcn_mfma_f32_16x16x32_f16(a00, bf0_, D0, 0, 0, 0);      \
        D0 = __builtin_amdgcn_mfma_f32_16x16x32_f16(a01, bf1_, D0, 0, 0, 0);      \
        D1 = __builtin_amdgcn_mfma_f32_16x16x32_f16(a10, bf0_, D1, 0, 0, 0);      \
        D1 = __builtin_amdgcn_mfma_f32_16x16x32_f16(a11, bf1_, D1, 0, 0, 0);      \
        D2 = __builtin_amdgcn_mfma_f32_16x16x32_f16(a20, bf0_, D2, 0, 0, 0);      \
        D2 = __builtin_amdgcn_mfma_f32_16x16x32_f16(a21, bf1_, D2, 0, 0, 0);      \
        D3 = __builtin_amdgcn_mfma_f32_16x16x32_f16(a30, bf0_, D3, 0, 0, 0);      \
        D3 = __builtin_amdgcn_mfma_f32_16x16x32_f16(a31, bf1_, D3, 0, 0, 0);      \
        const float ck_ = (CK);                                                   \
        y0 += ck_ * D0; y1 += ck_ * D1; y2 += ck_ * D2; y3 += ck_ * D3;           \
    }

#define TRIW1(Y, R, MR, NC)                                                      \
    { const int m_ = (MR) + (R);                                                 \
      if (m_ <= (NC)) ybuf[m_ * NDIM - (m_ * (m_ - 1)) / 2 + ((NC) - m_)] = Y[R]; }
#define TRIW(Y, MR, NC) \
    TRIW1(Y, 0, MR, NC) TRIW1(Y, 1, MR, NC) TRIW1(Y, 2, MR, NC) TRIW1(Y, 3, MR, NC)

__global__ __launch_bounds__(256, 4)
void spd_log_mfma(const void* __restrict__ xin,
                  float* __restrict__ out,
                  Coeffs co)
{
    __shared__ __align__(16) _Float16 planes[2][NDIM * PSTR];   // 2 x 9216 B

    const int b    = blockIdx.x;
    const int tid  = threadIdx.x;
    const int wave = tid >> 6;
    const int lane = tid & 63;
    const int l    = lane & 15;
    const int q    = lane >> 4;
    const int n0   = wave * 16;      // strip base column

    _Float16* const p0 = &planes[0][0];
    _Float16* const p1 = &planes[1][0];

    const bool isb = sniff_is_bf16(xin);

    // ---------------- stage: p0 = A2 = (X-mI)/2 (EXACT f16 for bf16 input) ----------------
    if (isb) {
        const uint2* xv = (const uint2*)((const unsigned short*)xin + (size_t)b * (NDIM * NDIM));
        #pragma unroll
        for (int r = 0; r < 4; ++r) {
            const int e4 = tid + r * 256;          // 1024 quads
            const int e0 = e4 * 4;
            const int row = e0 >> 6, col = e0 & 63;
            const uint2 w = xv[e4];
            union { unsigned u; float f; } u0, u1, u2, u3;
            u0.u = (w.x & 0xffffu) << 16; u1.u = (w.x & 0xffff0000u);
            u2.u = (w.y & 0xffffu) << 16; u3.u = (w.y & 0xffff0000u);
            const float v0 = u0.f - ((col + 0 == row) ? CMID : 0.f);
            const float v1 = u1.f - ((col + 1 == row) ? CMID : 0.f);
            const float v2 = u2.f - ((col + 2 == row) ? CMID : 0.f);
            const float v3 = u3.f - ((col + 3 == row) ? CMID : 0.f);
            f16x4 h0;
            h0[0] = (_Float16)(v0 * 0.5f); h0[1] = (_Float16)(v1 * 0.5f);
            h0[2] = (_Float16)(v2 * 0.5f); h0[3] = (_Float16)(v3 * 0.5f);
            *(f16x4*)&p0[row * PSTR + col] = h0;
        }
    } else {
        const float4* xv = (const float4*)((const float*)xin + (size_t)b * (NDIM * NDIM));
        #pragma unroll
        for (int r = 0; r < 4; ++r) {
            const int e4 = tid + r * 256;
            const int e0 = e4 * 4;
            const int row = e0 >> 6, col = e0 & 63;
            const float4 w = xv[e4];
            const float v0 = w.x - ((col + 0 == row) ? CMID : 0.f);
            const float v1 = w.y - ((col + 1 == row) ? CMID : 0.f);
            const float v2 = w.z - ((col + 2 == row) ? CMID : 0.f);
            const float v3 = w.w - ((col + 3 == row) ? CMID : 0.f);
            f16x4 h0;
            h0[0] = (_Float16)(v0 * 0.5f); h0[1] = (_Float16)(v1 * 0.5f);
            h0[2] = (_Float16)(v2 * 0.5f); h0[3] = (_Float16)(v3 * 0.5f);
            *(f16x4*)&p0[row * PSTR + col] = h0;
        }
    }
    __syncthreads();

    // ---------------- A-fragments: a{mt}{kt} = A2[16mt+l][32kt+8q+i], fixed ----------------
    const int ar = l * PSTR + 8 * q;
    const f16x8 a00 = *(const f16x8*)&p0[ar                 ];
    const f16x8 a01 = *(const f16x8*)&p0[ar + 32            ];
    const f16x8 a10 = *(const f16x8*)&p0[ar + 16 * PSTR     ];
    const f16x8 a11 = *(const f16x8*)&p0[ar + 16 * PSTR + 32];
    const f16x8 a20 = *(const f16x8*)&p0[ar + 32 * PSTR     ];
    const f16x8 a21 = *(const f16x8*)&p0[ar + 32 * PSTR + 32];
    const f16x8 a30 = *(const f16x8*)&p0[ar + 48 * PSTR     ];
    const f16x8 a31 = *(const f16x8*)&p0[ar + 48 * PSTR + 32];

    // ---------------- init C/D state: sa = V0 = I, sb = V1 = T1 = A2/2 ----------------
    // Tile mt element (row 16mt+4q+r, col n0+l); T1[row][col] read via A2 symmetry.
    const int nc  = n0 + l;
    const float cc0 = co.c[0], cc1 = co.c[1];
    f32x4 sa0, sa1, sa2, sa3;
    f32x4 sb0, sb1, sb2, sb3;
    f32x4 y0, y1, y2, y3;

#define INIT_TILE(SB, SA, Y, MT)                                                 \
    {                                                                            \
        const f16x4 tv = *(const f16x4*)&p0[nc * PSTR + 16 * (MT) + 4 * q];      \
        const float t0_ = 0.5f * (float)tv[0], t1_ = 0.5f * (float)tv[1];        \
        const float t2_ = 0.5f * (float)tv[2], t3_ = 0.5f * (float)tv[3];        \
        SB[0] = t0_; SB[1] = t1_; SB[2] = t2_; SB[3] = t3_;                      \
        const float d0_ = (16 * (MT) + 4 * q + 0 == nc) ? 1.f : 0.f;             \
        const float d1_ = (16 * (MT) + 4 * q + 1 == nc) ? 1.f : 0.f;             \
        const float d2_ = (16 * (MT) + 4 * q + 2 == nc) ? 1.f : 0.f;             \
        const float d3_ = (16 * (MT) + 4 * q + 3 == nc) ? 1.f : 0.f;             \
        SA[0] = d0_; SA[1] = d1_; SA[2] = d2_; SA[3] = d3_;                      \
        Y[0] = cc1 * t0_ + cc0 * d0_; Y[1] = cc1 * t1_ + cc0 * d1_;              \
        Y[2] = cc1 * t2_ + cc0 * d2_; Y[3] = cc1 * t3_ + cc0 * d3_;              \
    }
    INIT_TILE(sb0, sa0, y0, 0)
    INIT_TILE(sb1, sa1, y1, 1)
    INIT_TILE(sb2, sa2, y2, 2)
    INIT_TILE(sb3, sa3, y3, 3)
#undef INIT_TILE
    __syncthreads();   // all waves done reading p0 before anyone reuses it (ybuf)

    // ---------------- scratch offsets (f16 units, loop-invariant) ----------------
    const int sw  = wave * 1024;
    const int qh  = q >> 1, qlo = q & 1;
    const int wa0 = sw +   0 + qh * 128 + ((l ^ (    2 * qh)) << 3) + (qlo << 2);
    const int wa1 = sw + 256 + qh * 128 + ((l ^ (4 + 2 * qh)) << 3) + (qlo << 2);
    const int wa2 = sw + 512 + qh * 128 + ((l ^ (    2 * qh)) << 3) + (qlo << 2);
    const int wa3 = sw + 768 + qh * 128 + ((l ^ (4 + 2 * qh)) << 3) + (qlo << 2);
    const int ra0 = sw + (    qh) * 256 + qlo * 128 + ((l ^ (2 * q)) << 3);
    const int ra1 = sw + (2 + qh) * 256 + qlo * 128 + ((l ^ (2 * q)) << 3);

    // ---------------- Chebyshev recurrence: 18 steps, ZERO barriers ----------------
    // even k: frag = f16(-sb) = sigma_k*T_{k-1}; D=sa (C-in = V_{k-2}); odd: frag = +f16(sa).
    #pragma unroll
    for (int kk = 2; kk < NDEG; kk += 2) {
        XCHG_STEP(sb0, sb1, sb2, sb3, sa0, sa1, sa2, sa3, co.c[kk],     -)
        XCHG_STEP(sa0, sa1, sa2, sa3, sb0, sb1, sb2, sb3, co.c[kk + 1], +)
    }

    // ---------------- output: stage triu in LDS (p0 region), coalesced stores ----------------
    float* ybuf = (float*)p0;      // 8320 B <= 9216 B
    TRIW(y0,      4 * q, nc)
    TRIW(y1, 16 + 4 * q, nc)
    TRIW(y2, 32 + 4 * q, nc)
    TRIW(y3, 48 + 4 * q, nc)
    __syncthreads();

    float4* dst = (float4*)(out + (size_t)b * TRI);
    const float4* src = (const float4*)ybuf;
    for (int e = tid; e < TRI / 4; e += 256)
        dst[e] = src[e];
}

extern "C" void kernel_launch(void* const* d_in, const int* in_sizes, int n_in,
                              void* d_out, int out_size, void* d_ws, size_t ws_size,
                              hipStream_t stream)
{
    (void)n_in; (void)d_ws; (void)ws_size; (void)out_size;

    // Chebyshev coefficients of log on [a,b] = [0.75, 8.75]:
    // log(m + h t) = log(h/(2g)) + sum_{k>=1} 2(-1)^{k+1} g^k / k * T_k(t)
    // h = 4 (power of two), m = 4.75. Signs sigma_k (period 4: +,+,-,-) folded in.
    const double a = 0.75, bnd = 8.75;
    const double m = 0.5 * (a + bnd), h = 0.5 * (bnd - a);
    const double alpha = h / m;
    const double gam = (1.0 - sqrt(1.0 - alpha * alpha)) / alpha;

    Coeffs co;
    co.c[0] = (float)log(h / (2.0 * gam));
    double g = 1.0;
    for (int k = 1; k <= NDEG; ++k) {
        g *= gam;
        const double ck  = (((k & 1) ? 2.0 : -2.0) * g) / (double)k;
        const double sig = ((k >> 1) & 1) ? -1.0 : 1.0;
        co.c[k] = (float)(ck * sig);
    }

    const int B = in_sizes[0] / (NDIM * NDIM);
    spd_log_mfma<<<B, 256, 0, stream>>>(d_in[0], (float*)d_out, co);
}

// Round 7
// 239.103 us; speedup vs baseline: 2.4998x; 2.4998x over previous
//
#include <hip/hip_runtime.h>
#include <hip/hip_bf16.h>
#include <cmath>

#define NDIM  64
#define PSTR  72        // LDS plane row stride in f16 (144 B, 16B-aligned rows)
#define NDEG  19        // Chebyshev degree for log on [0.75, 8.75]; trunc err ~1.3e-6
#define TRI   2080      // 64*65/2
#define CMID  4.75f     // interval midpoint m; h = 4

struct Coeffs {
    float c[NDEG + 1];  // c'_k = sigma_k * c_k  (sigma = +,+,-,-,+,+,...)
};

typedef _Float16 f16x8 __attribute__((ext_vector_type(8)));
typedef _Float16 f16x4 __attribute__((ext_vector_type(4)));
typedef float    f32x4 __attribute__((ext_vector_type(4)));

// SPD => symmetric under the TRUE dtype; wrong reinterpretation gives O(1)/NaN residual.
__device__ __forceinline__ bool sniff_is_bf16(const void* xin)
{
    const float*          f0 = (const float*)xin;
    const unsigned short* h0 = (const unsigned short*)xin;
    const int pi[8] = {1, 3, 5, 2, 4, 6, 7, 8};
    const int pj[8] = {2, 7, 11, 9, 13, 17, 23, 31};
    float fsym = 0.f, bsym = 0.f;
    #pragma unroll
    for (int p = 0; p < 8; ++p) {
        const int i = pi[p], j = pj[p];
        fsym += fabsf(f0[i * NDIM + j] - f0[j * NDIM + i]);
        union { unsigned u; float f; } ua, ub;
        ua.u = ((unsigned)h0[i * NDIM + j]) << 16;
        ub.u = ((unsigned)h0[j * NDIM + i]) << 16;
        bsym += fabsf(ua.f - ub.f);
    }
    if (fsym != fsym) return true;
    if (bsym != bsym) return false;
    return bsym < fsym;
}

// One 64x64 matrix per 256-thread block (4 waves). COLUMN-STRIP decomposition:
// wave w owns cols n0 = 16w..16w+15, ALL 64 rows, as 4 stacked 16x16 C/D tiles.
// The recurrence T_{k+1}[:,strip] = A2*T_k[:,strip] - T_{k-1}[:,strip] is closed
// per wave -> ZERO barriers in the 17-step loop; B-operands are rebuilt from the
// wave's OWN C/D registers via a wave-private LDS scratch (4 ds_write_b64 +
// lgkmcnt(0) + 2 ds_read_b128 per step). Correctness of the exchange indexing
// and sign algebra HW-verified in round 6 (absmax == round-5 reference).
//
// Sign algebra: V_k = sigma_k T_k (sigma period 4: +,+,-,-), every step is one
// in-place set = mfma(A2, frag, set) with C-in = V_{k-2},
// frag = f16((k even ? - : +) V_{k-1}); c'_k = sigma_k c_k host-folded.
// A2 = (X-mI)/2 and T1 = A2/2 are EXACT in f16 for bf16 input.
//
// Register budget (round-6 lesson): steady-state live set ~106 VGPRs
// (8 afrag=32, sa/sb=32, y=16, addrs+temps~26). __launch_bounds__(256,4)'s
// 128-reg cap split arch/acc 64/64 -> spill -> 0.65/1.3 GB scratch traffic.
// (256,2) raises the cap to 256; occupancy then limited to ~4 blocks/CU by
// VGPRs, same as round 5, with 3 barriers total instead of 36.
//
// Scratch discipline (rule #20): all persistent state individually named, all
// vector subscripts literal, no pragma-loops inside macros.

#define XCHG_STEP(S0, S1, S2, S3, D0, D1, D2, D3, CK, SGN)                        \
    {                                                                             \
        f16x4 w0_, w1_, w2_, w3_;                                                 \
        w0_[0]=(_Float16)(SGN S0[0]); w0_[1]=(_Float16)(SGN S0[1]);               \
        w0_[2]=(_Float16)(SGN S0[2]); w0_[3]=(_Float16)(SGN S0[3]);               \
        w1_[0]=(_Float16)(SGN S1[0]); w1_[1]=(_Float16)(SGN S1[1]);               \
        w1_[2]=(_Float16)(SGN S1[2]); w1_[3]=(_Float16)(SGN S1[3]);               \
        w2_[0]=(_Float16)(SGN S2[0]); w2_[1]=(_Float16)(SGN S2[1]);               \
        w2_[2]=(_Float16)(SGN S2[2]); w2_[3]=(_Float16)(SGN S2[3]);               \
        w3_[0]=(_Float16)(SGN S3[0]); w3_[1]=(_Float16)(SGN S3[1]);               \
        w3_[2]=(_Float16)(SGN S3[2]); w3_[3]=(_Float16)(SGN S3[3]);               \
        *(f16x4*)&p1[wa0] = w0_;  *(f16x4*)&p1[wa1] = w1_;                        \
        *(f16x4*)&p1[wa2] = w2_;  *(f16x4*)&p1[wa3] = w3_;                        \
        asm volatile("s_waitcnt lgkmcnt(0)" ::: "memory");                        \
        const f16x8 bf0_ = *(const f16x8*)&p1[ra0];                               \
        const f16x8 bf1_ = *(const f16x8*)&p1[ra1];                               \
        D0 = __builtin_amdgcn_mfma_f32_16x16x32_f16(a00, bf0_, D0, 0, 0, 0);      \
        D0 = __builtin_amdgcn_mfma_f32_16x16x32_f16(a01, bf1_, D0, 0, 0, 0);      \
        D1 = __builtin_amdgcn_mfma_f32_16x16x32_f16(a10, bf0_, D1, 0, 0, 0);      \
        D1 = __builtin_amdgcn_mfma_f32_16x16x32_f16(a11, bf1_, D1, 0, 0, 0);      \
        D2 = __builtin_amdgcn_mfma_f32_16x16x32_f16(a20, bf0_, D2, 0, 0, 0);      \
        D2 = __builtin_amdgcn_mfma_f32_16x16x32_f16(a21, bf1_, D2, 0, 0, 0);      \
        D3 = __builtin_amdgcn_mfma_f32_16x16x32_f16(a30, bf0_, D3, 0, 0, 0);      \
        D3 = __builtin_amdgcn_mfma_f32_16x16x32_f16(a31, bf1_, D3, 0, 0, 0);      \
        const float ck_ = (CK);                                                   \
        y0 += ck_ * D0; y1 += ck_ * D1; y2 += ck_ * D2; y3 += ck_ * D3;           \
    }

#define TRIW1(Y, R, MR, NC)                                                      \
    { const int m_ = (MR) + (R);                                                 \
      if (m_ <= (NC)) ybuf[m_ * NDIM - (m_ * (m_ - 1)) / 2 + ((NC) - m_)] = Y[R]; }
#define TRIW(Y, MR, NC) \
    TRIW1(Y, 0, MR, NC) TRIW1(Y, 1, MR, NC) TRIW1(Y, 2, MR, NC) TRIW1(Y, 3, MR, NC)

__global__ __launch_bounds__(256, 2)
void spd_log_mfma(const void* __restrict__ xin,
                  float* __restrict__ out,
                  Coeffs co)
{
    __shared__ __align__(16) _Float16 planes[2][NDIM * PSTR];   // 2 x 9216 B

    const int b    = blockIdx.x;
    const int tid  = threadIdx.x;
    const int wave = tid >> 6;
    const int lane = tid & 63;
    const int l    = lane & 15;
    const int q    = lane >> 4;
    const int n0   = wave * 16;      // strip base column

    _Float16* const p0 = &planes[0][0];
    _Float16* const p1 = &planes[1][0];

    const bool isb = sniff_is_bf16(xin);

    // ---------------- stage: p0 = A2 = (X-mI)/2 (EXACT f16 for bf16 input) ----------------
    if (isb) {
        const uint2* xv = (const uint2*)((const unsigned short*)xin + (size_t)b * (NDIM * NDIM));
        #pragma unroll
        for (int r = 0; r < 4; ++r) {
            const int e4 = tid + r * 256;          // 1024 quads
            const int e0 = e4 * 4;
            const int row = e0 >> 6, col = e0 & 63;
            const uint2 w = xv[e4];
            union { unsigned u; float f; } u0, u1, u2, u3;
            u0.u = (w.x & 0xffffu) << 16; u1.u = (w.x & 0xffff0000u);
            u2.u = (w.y & 0xffffu) << 16; u3.u = (w.y & 0xffff0000u);
            const float v0 = u0.f - ((col + 0 == row) ? CMID : 0.f);
            const float v1 = u1.f - ((col + 1 == row) ? CMID : 0.f);
            const float v2 = u2.f - ((col + 2 == row) ? CMID : 0.f);
            const float v3 = u3.f - ((col + 3 == row) ? CMID : 0.f);
            f16x4 h0;
            h0[0] = (_Float16)(v0 * 0.5f); h0[1] = (_Float16)(v1 * 0.5f);
            h0[2] = (_Float16)(v2 * 0.5f); h0[3] = (_Float16)(v3 * 0.5f);
            *(f16x4*)&p0[row * PSTR + col] = h0;
        }
    } else {
        const float4* xv = (const float4*)((const float*)xin + (size_t)b * (NDIM * NDIM));
        #pragma unroll
        for (int r = 0; r < 4; ++r) {
            const int e4 = tid + r * 256;
            const int e0 = e4 * 4;
            const int row = e0 >> 6, col = e0 & 63;
            const float4 w = xv[e4];
            const float v0 = w.x - ((col + 0 == row) ? CMID : 0.f);
            const float v1 = w.y - ((col + 1 == row) ? CMID : 0.f);
            const float v2 = w.z - ((col + 2 == row) ? CMID : 0.f);
            const float v3 = w.w - ((col + 3 == row) ? CMID : 0.f);
            f16x4 h0;
            h0[0] = (_Float16)(v0 * 0.5f); h0[1] = (_Float16)(v1 * 0.5f);
            h0[2] = (_Float16)(v2 * 0.5f); h0[3] = (_Float16)(v3 * 0.5f);
            *(f16x4*)&p0[row * PSTR + col] = h0;
        }
    }
    __syncthreads();

    // ---------------- A-fragments: a{mt}{kt} = A2[16mt+l][32kt+8q+i], fixed ----------------
    const int ar = l * PSTR + 8 * q;
    const f16x8 a00 = *(const f16x8*)&p0[ar                 ];
    const f16x8 a01 = *(const f16x8*)&p0[ar + 32            ];
    const f16x8 a10 = *(const f16x8*)&p0[ar + 16 * PSTR     ];
    const f16x8 a11 = *(const f16x8*)&p0[ar + 16 * PSTR + 32];
    const f16x8 a20 = *(const f16x8*)&p0[ar + 32 * PSTR     ];
    const f16x8 a21 = *(const f16x8*)&p0[ar + 32 * PSTR + 32];
    const f16x8 a30 = *(const f16x8*)&p0[ar + 48 * PSTR     ];
    const f16x8 a31 = *(const f16x8*)&p0[ar + 48 * PSTR + 32];

    // ---------------- init C/D state: sa = V0 = I, sb = V1 = T1 = A2/2 ----------------
    // Tile mt element (row 16mt+4q+r, col n0+l); T1[row][col] read via A2 symmetry.
    const int nc  = n0 + l;
    const float cc0 = co.c[0], cc1 = co.c[1];
    f32x4 sa0, sa1, sa2, sa3;
    f32x4 sb0, sb1, sb2, sb3;
    f32x4 y0, y1, y2, y3;

#define INIT_TILE(SB, SA, Y, MT)                                                 \
    {                                                                            \
        const f16x4 tv = *(const f16x4*)&p0[nc * PSTR + 16 * (MT) + 4 * q];      \
        const float t0_ = 0.5f * (float)tv[0], t1_ = 0.5f * (float)tv[1];        \
        const float t2_ = 0.5f * (float)tv[2], t3_ = 0.5f * (float)tv[3];        \
        SB[0] = t0_; SB[1] = t1_; SB[2] = t2_; SB[3] = t3_;                      \
        const float d0_ = (16 * (MT) + 4 * q + 0 == nc) ? 1.f : 0.f;             \
        const float d1_ = (16 * (MT) + 4 * q + 1 == nc) ? 1.f : 0.f;             \
        const float d2_ = (16 * (MT) + 4 * q + 2 == nc) ? 1.f : 0.f;             \
        const float d3_ = (16 * (MT) + 4 * q + 3 == nc) ? 1.f : 0.f;             \
        SA[0] = d0_; SA[1] = d1_; SA[2] = d2_; SA[3] = d3_;                      \
        Y[0] = cc1 * t0_ + cc0 * d0_; Y[1] = cc1 * t1_ + cc0 * d1_;              \
        Y[2] = cc1 * t2_ + cc0 * d2_; Y[3] = cc1 * t3_ + cc0 * d3_;              \
    }
    INIT_TILE(sb0, sa0, y0, 0)
    INIT_TILE(sb1, sa1, y1, 1)
    INIT_TILE(sb2, sa2, y2, 2)
    INIT_TILE(sb3, sa3, y3, 3)
#undef INIT_TILE
    __syncthreads();   // all waves done reading p0 before anyone reuses it (ybuf)

    // ---------------- scratch offsets (f16 units, loop-invariant) ----------------
    const int sw  = wave * 1024;
    const int qh  = q >> 1, qlo = q & 1;
    const int wa0 = sw +   0 + qh * 128 + ((l ^ (    2 * qh)) << 3) + (qlo << 2);
    const int wa1 = sw + 256 + qh * 128 + ((l ^ (4 + 2 * qh)) << 3) + (qlo << 2);
    const int wa2 = sw + 512 + qh * 128 + ((l ^ (    2 * qh)) << 3) + (qlo << 2);
    const int wa3 = sw + 768 + qh * 128 + ((l ^ (4 + 2 * qh)) << 3) + (qlo << 2);
    const int ra0 = sw + (    qh) * 256 + qlo * 128 + ((l ^ (2 * q)) << 3);
    const int ra1 = sw + (2 + qh) * 256 + qlo * 128 + ((l ^ (2 * q)) << 3);

    // ---------------- Chebyshev recurrence: 18 steps, ZERO barriers ----------------
    // even k: frag = f16(-sb) = sigma_k*T_{k-1}, D=sa (C-in = V_{k-2}); odd: frag = +f16(sa).
    for (int kk = 2; kk < NDEG; kk += 2) {
        XCHG_STEP(sb0, sb1, sb2, sb3, sa0, sa1, sa2, sa3, co.c[kk],     -)
        XCHG_STEP(sa0, sa1, sa2, sa3, sb0, sb1, sb2, sb3, co.c[kk + 1], +)
    }

    // ---------------- output: stage triu in LDS (p0 region), coalesced stores ----------------
    float* ybuf = (float*)p0;      // 8320 B <= 9216 B
    TRIW(y0,      4 * q, nc)
    TRIW(y1, 16 + 4 * q, nc)
    TRIW(y2, 32 + 4 * q, nc)
    TRIW(y3, 48 + 4 * q, nc)
    __syncthreads();

    float4* dst = (float4*)(out + (size_t)b * TRI);
    const float4* src = (const float4*)ybuf;
    for (int e = tid; e < TRI / 4; e += 256)
        dst[e] = src[e];
}

extern "C" void kernel_launch(void* const* d_in, const int* in_sizes, int n_in,
                              void* d_out, int out_size, void* d_ws, size_t ws_size,
                              hipStream_t stream)
{
    (void)n_in; (void)d_ws; (void)ws_size; (void)out_size;

    // Chebyshev coefficients of log on [a,b] = [0.75, 8.75]:
    // log(m + h t) = log(h/(2g)) + sum_{k>=1} 2(-1)^{k+1} g^k / k * T_k(t)
    // h = 4 (power of two), m = 4.75. Signs sigma_k (period 4: +,+,-,-) folded in.
    const double a = 0.75, bnd = 8.75;
    const double m = 0.5 * (a + bnd), h = 0.5 * (bnd - a);
    const double alpha = h / m;
    const double gam = (1.0 - sqrt(1.0 - alpha * alpha)) / alpha;

    Coeffs co;
    co.c[0] = (float)log(h / (2.0 * gam));
    double g = 1.0;
    for (int k = 1; k <= NDEG; ++k) {
        g *= gam;
        const double ck  = (((k & 1) ? 2.0 : -2.0) * g) / (double)k;
        const double sig = ((k >> 1) & 1) ? -1.0 : 1.0;
        co.c[k] = (float)(ck * sig);
    }

    const int B = in_sizes[0] / (NDIM * NDIM);
    spd_log_mfma<<<B, 256, 0, stream>>>(d_in[0], (float*)d_out, co);
}

// Round 9
// 236.893 us; speedup vs baseline: 2.5231x; 1.0093x over previous
//
#include <hip/hip_runtime.h>
#include <hip/hip_bf16.h>
#include <cmath>

#define NDIM  64
#define PSTR  72        // LDS plane row stride in f16 (144 B, 16B-aligned rows)
#define NDEG  19        // Chebyshev degree for log on [0.75, 8.75]; trunc err ~1.3e-6
#define TRI   2080      // 64*65/2
#define CMID  4.75f     // interval midpoint m; h = 4

struct Coeffs {
    float c[NDEG + 1];  // c'_k = sigma_k * c_k  (sigma = +,+,-,-,+,+,...)
};

typedef _Float16 f16x8 __attribute__((ext_vector_type(8)));
typedef _Float16 f16x4 __attribute__((ext_vector_type(4)));
typedef float    f32x4 __attribute__((ext_vector_type(4)));

// SPD => symmetric under the TRUE dtype; wrong reinterpretation gives O(1)/NaN residual.
__device__ __forceinline__ bool sniff_is_bf16(const void* xin)
{
    const float*          f0 = (const float*)xin;
    const unsigned short* h0 = (const unsigned short*)xin;
    const int pi[8] = {1, 3, 5, 2, 4, 6, 7, 8};
    const int pj[8] = {2, 7, 11, 9, 13, 17, 23, 31};
    float fsym = 0.f, bsym = 0.f;
    #pragma unroll
    for (int p = 0; p < 8; ++p) {
        const int i = pi[p], j = pj[p];
        fsym += fabsf(f0[i * NDIM + j] - f0[j * NDIM + i]);
        union { unsigned u; float f; } ua, ub;
        ua.u = ((unsigned)h0[i * NDIM + j]) << 16;
        ub.u = ((unsigned)h0[j * NDIM + i]) << 16;
        bsym += fabsf(ua.f - ub.f);
    }
    if (fsym != fsym) return true;
    if (bsym != bsym) return false;
    return bsym < fsym;
}

// One 64x64 matrix per 256-thread block (4 waves). COLUMN-STRIP decomposition:
// wave w owns cols n0 = 16w..16w+15, ALL 64 rows, as 4 stacked 16x16 C/D tiles.
// T_{k+1}[:,strip] = A2*T_k[:,strip] - T_{k-1}[:,strip] is closed per wave ->
// ZERO barriers in the 17-step loop; B-operands rebuilt from the wave's OWN C/D
// registers through a wave-private LDS scratch.
//
// Round-8 latency fix: NO manual lgkmcnt(0) drain. DS ops from one wave execute
// in order in the LDS pipe, and the writes/reads are compiler-visible (may-alias
// => program order preserved; compiler emits counted lgkmcnt(3) for bf0, 0 for
// bf1). Interleave w0,w1 -> r0 -> w2,w3 -> r1: r0's data only depends on tile
// 0/1 writes, r1 on tile 2/3, so r1 latency hides under the first 4 MFMAs.
// setprio(1) around the MFMA cluster: waves here are barrier-free/desynced
// (attn-like regime where setprio measured +4-7%, not lockstep-GEMM null).
//
// Sign algebra (HW-verified r6/r7): V_k = sigma_k T_k (sigma period 4: +,+,-,-),
// every step is one in-place set = mfma(A2, frag, set) with C-in = V_{k-2},
// frag = f16((k even ? - : +) V_{k-1}); c'_k = sigma_k c_k host-folded.
// A2 = (X-mI)/2 and T1 = A2/2 are EXACT in f16 for bf16 input.
//
// Register budget (r6 lesson): live set ~106 VGPRs; launch_bounds(256,2) so the
// allocator gets 256 regs (measured r7: VGPR 60, no spill, clean HBM traffic).
// Scratch discipline (rule #20): named state, literal subscripts only.

#define XCHG_STEP(S0, S1, S2, S3, D0, D1, D2, D3, CK, SGN)                        \
    {                                                                             \
        f16x4 w0_, w1_, w2_, w3_;                                                 \
        w0_[0]=(_Float16)(SGN S0[0]); w0_[1]=(_Float16)(SGN S0[1]);               \
        w0_[2]=(_Float16)(SGN S0[2]); w0_[3]=(_Float16)(SGN S0[3]);               \
        w1_[0]=(_Float16)(SGN S1[0]); w1_[1]=(_Float16)(SGN S1[1]);               \
        w1_[2]=(_Float16)(SGN S1[2]); w1_[3]=(_Float16)(SGN S1[3]);               \
        *(f16x4*)&p1[wa0] = w0_;  *(f16x4*)&p1[wa1] = w1_;                        \
        const f16x8 bf0_ = *(const f16x8*)&p1[ra0];    /* after wa0,wa1: in-order DS */ \
        w2_[0]=(_Float16)(SGN S2[0]); w2_[1]=(_Float16)(SGN S2[1]);               \
        w2_[2]=(_Float16)(SGN S2[2]); w2_[3]=(_Float16)(SGN S2[3]);               \
        w3_[0]=(_Float16)(SGN S3[0]); w3_[1]=(_Float16)(SGN S3[1]);               \
        w3_[2]=(_Float16)(SGN S3[2]); w3_[3]=(_Float16)(SGN S3[3]);               \
        *(f16x4*)&p1[wa2] = w2_;  *(f16x4*)&p1[wa3] = w3_;                        \
        const f16x8 bf1_ = *(const f16x8*)&p1[ra1];    /* after wa2,wa3 */        \
        __builtin_amdgcn_s_setprio(1);                                            \
        D0 = __builtin_amdgcn_mfma_f32_16x16x32_f16(a00, bf0_, D0, 0, 0, 0);      \
        D1 = __builtin_amdgcn_mfma_f32_16x16x32_f16(a10, bf0_, D1, 0, 0, 0);      \
        D2 = __builtin_amdgcn_mfma_f32_16x16x32_f16(a20, bf0_, D2, 0, 0, 0);      \
        D3 = __builtin_amdgcn_mfma_f32_16x16x32_f16(a30, bf0_, D3, 0, 0, 0);      \
        D0 = __builtin_amdgcn_mfma_f32_16x16x32_f16(a01, bf1_, D0, 0, 0, 0);      \
        D1 = __builtin_amdgcn_mfma_f32_16x16x32_f16(a11, bf1_, D1, 0, 0, 0);      \
        D2 = __builtin_amdgcn_mfma_f32_16x16x32_f16(a21, bf1_, D2, 0, 0, 0);      \
        D3 = __builtin_amdgcn_mfma_f32_16x16x32_f16(a31, bf1_, D3, 0, 0, 0);      \
        __builtin_amdgcn_s_setprio(0);                                            \
        const float ck_ = (CK);                                                   \
        y0 += ck_ * D0; y1 += ck_ * D1; y2 += ck_ * D2; y3 += ck_ * D3;           \
    }

#define TRIW1(Y, R, MR, NC)                                                      \
    { const int m_ = (MR) + (R);                                                 \
      if (m_ <= (NC)) ybuf[m_ * NDIM - (m_ * (m_ - 1)) / 2 + ((NC) - m_)] = Y[R]; }
#define TRIW(Y, MR, NC) \
    TRIW1(Y, 0, MR, NC) TRIW1(Y, 1, MR, NC) TRIW1(Y, 2, MR, NC) TRIW1(Y, 3, MR, NC)

__global__ __launch_bounds__(256, 2)
void spd_log_mfma(const void* __restrict__ xin,
                  float* __restrict__ out,
                  Coeffs co)
{
    __shared__ __align__(16) _Float16 planes[2][NDIM * PSTR];   // 2 x 9216 B

    const int b    = blockIdx.x;
    const int tid  = threadIdx.x;
    const int wave = tid >> 6;
    const int lane = tid & 63;
    const int l    = lane & 15;
    const int q    = lane >> 4;
    const int n0   = wave * 16;      // strip base column

    _Float16* const p0 = &planes[0][0];
    _Float16* const p1 = &planes[1][0];

    const bool isb = sniff_is_bf16(xin);

    // ---------------- stage: p0 = A2 = (X-mI)/2 (EXACT f16 for bf16 input) ----------------
    if (isb) {
        const uint2* xv = (const uint2*)((const unsigned short*)xin + (size_t)b * (NDIM * NDIM));
        #pragma unroll
        for (int r = 0; r < 4; ++r) {
            const int e4 = tid + r * 256;          // 1024 quads
            const int e0 = e4 * 4;
            const int row = e0 >> 6, col = e0 & 63;
            const uint2 w = xv[e4];
            union { unsigned u; float f; } u0, u1, u2, u3;
            u0.u = (w.x & 0xffffu) << 16; u1.u = (w.x & 0xffff0000u);
            u2.u = (w.y & 0xffffu) << 16; u3.u = (w.y & 0xffff0000u);
            const float v0 = u0.f - ((col + 0 == row) ? CMID : 0.f);
            const float v1 = u1.f - ((col + 1 == row) ? CMID : 0.f);
            const float v2 = u2.f - ((col + 2 == row) ? CMID : 0.f);
            const float v3 = u3.f - ((col + 3 == row) ? CMID : 0.f);
            f16x4 h0;
            h0[0] = (_Float16)(v0 * 0.5f); h0[1] = (_Float16)(v1 * 0.5f);
            h0[2] = (_Float16)(v2 * 0.5f); h0[3] = (_Float16)(v3 * 0.5f);
            *(f16x4*)&p0[row * PSTR + col] = h0;
        }
    } else {
        const float4* xv = (const float4*)((const float*)xin + (size_t)b * (NDIM * NDIM));
        #pragma unroll
        for (int r = 0; r < 4; ++r) {
            const int e4 = tid + r * 256;
            const int e0 = e4 * 4;
            const int row = e0 >> 6, col = e0 & 63;
            const float4 w = xv[e4];
            const float v0 = w.x - ((col + 0 == row) ? CMID : 0.f);
            const float v1 = w.y - ((col + 1 == row) ? CMID : 0.f);
            const float v2 = w.z - ((col + 2 == row) ? CMID : 0.f);
            const float v3 = w.w - ((col + 3 == row) ? CMID : 0.f);
            f16x4 h0;
            h0[0] = (_Float16)(v0 * 0.5f); h0[1] = (_Float16)(v1 * 0.5f);
            h0[2] = (_Float16)(v2 * 0.5f); h0[3] = (_Float16)(v3 * 0.5f);
            *(f16x4*)&p0[row * PSTR + col] = h0;
        }
    }
    __syncthreads();

    // ---------------- A-fragments: a{mt}{kt} = A2[16mt+l][32kt+8q+i], fixed ----------------
    const int ar = l * PSTR + 8 * q;
    const f16x8 a00 = *(const f16x8*)&p0[ar                 ];
    const f16x8 a01 = *(const f16x8*)&p0[ar + 32            ];
    const f16x8 a10 = *(const f16x8*)&p0[ar + 16 * PSTR     ];
    const f16x8 a11 = *(const f16x8*)&p0[ar + 16 * PSTR + 32];
    const f16x8 a20 = *(const f16x8*)&p0[ar + 32 * PSTR     ];
    const f16x8 a21 = *(const f16x8*)&p0[ar + 32 * PSTR + 32];
    const f16x8 a30 = *(const f16x8*)&p0[ar + 48 * PSTR     ];
    const f16x8 a31 = *(const f16x8*)&p0[ar + 48 * PSTR + 32];

    // ---------------- init C/D state: sa = V0 = I, sb = V1 = T1 = A2/2 ----------------
    // Tile mt element (row 16mt+4q+r, col n0+l); T1[row][col] read via A2 symmetry.
    const int nc  = n0 + l;
    const float cc0 = co.c[0], cc1 = co.c[1];
    f32x4 sa0, sa1, sa2, sa3;
    f32x4 sb0, sb1, sb2, sb3;
    f32x4 y0, y1, y2, y3;

#define INIT_TILE(SB, SA, Y, MT)                                                 \
    {                                                                            \
        const f16x4 tv = *(const f16x4*)&p0[nc * PSTR + 16 * (MT) + 4 * q];      \
        const float t0_ = 0.5f * (float)tv[0], t1_ = 0.5f * (float)tv[1];        \
        const float t2_ = 0.5f * (float)tv[2], t3_ = 0.5f * (float)tv[3];        \
        SB[0] = t0_; SB[1] = t1_; SB[2] = t2_; SB[3] = t3_;                      \
        const float d0_ = (16 * (MT) + 4 * q + 0 == nc) ? 1.f : 0.f;             \
        const float d1_ = (16 * (MT) + 4 * q + 1 == nc) ? 1.f : 0.f;             \
        const float d2_ = (16 * (MT) + 4 * q + 2 == nc) ? 1.f : 0.f;             \
        const float d3_ = (16 * (MT) + 4 * q + 3 == nc) ? 1.f : 0.f;             \
        SA[0] = d0_; SA[1] = d1_; SA[2] = d2_; SA[3] = d3_;                      \
        Y[0] = cc1 * t0_ + cc0 * d0_; Y[1] = cc1 * t1_ + cc0 * d1_;              \
        Y[2] = cc1 * t2_ + cc0 * d2_; Y[3] = cc1 * t3_ + cc0 * d3_;              \
    }
    INIT_TILE(sb0, sa0, y0, 0)
    INIT_TILE(sb1, sa1, y1, 1)
    INIT_TILE(sb2, sa2, y2, 2)
    INIT_TILE(sb3, sa3, y3, 3)
#undef INIT_TILE
    __syncthreads();   // all waves done reading p0 before anyone reuses it (ybuf)

    // ---------------- scratch offsets (f16 units, loop-invariant) ----------------
    const int sw  = wave * 1024;
    const int qh  = q >> 1, qlo = q & 1;
    const int wa0 = sw +   0 + qh * 128 + ((l ^ (    2 * qh)) << 3) + (qlo << 2);
    const int wa1 = sw + 256 + qh * 128 + ((l ^ (4 + 2 * qh)) << 3) + (qlo << 2);
    const int wa2 = sw + 512 + qh * 128 + ((l ^ (    2 * qh)) << 3) + (qlo << 2);
    const int wa3 = sw + 768 + qh * 128 + ((l ^ (4 + 2 * qh)) << 3) + (qlo << 2);
    const int ra0 = sw + (    qh) * 256 + qlo * 128 + ((l ^ (2 * q)) << 3);
    const int ra1 = sw + (2 + qh) * 256 + qlo * 128 + ((l ^ (2 * q)) << 3);

    // ---------------- Chebyshev recurrence: 18 steps, ZERO barriers ----------------
    // even k: frag = f16(-sb) = sigma_k*T_{k-1}, D=sa (C-in = V_{k-2}); odd: frag = +f16(sa).
    for (int kk = 2; kk < NDEG; kk += 2) {
        XCHG_STEP(sb0, sb1, sb2, sb3, sa0, sa1, sa2, sa3, co.c[kk],     -)
        XCHG_STEP(sa0, sa1, sa2, sa3, sb0, sb1, sb2, sb3, co.c[kk + 1], +)
    }

    // ---------------- output: stage triu in LDS (p0 region), coalesced stores ----------------
    float* ybuf = (float*)p0;      // 8320 B <= 9216 B
    TRIW(y0,      4 * q, nc)
    TRIW(y1, 16 + 4 * q, nc)
    TRIW(y2, 32 + 4 * q, nc)
    TRIW(y3, 48 + 4 * q, nc)
    __syncthreads();

    float4* dst = (float4*)(out + (size_t)b * TRI);
    const float4* src = (const float4*)ybuf;
    for (int e = tid; e < TRI / 4; e += 256)
        dst[e] = src[e];
}

extern "C" void kernel_launch(void* const* d_in, const int* in_sizes, int n_in,
                              void* d_out, int out_size, void* d_ws, size_t ws_size,
                              hipStream_t stream)
{
    (void)n_in; (void)d_ws; (void)ws_size; (void)out_size;

    // Chebyshev coefficients of log on [a,b] = [0.75, 8.75]:
    // log(m + h t) = log(h/(2g)) + sum_{k>=1} 2(-1)^{k+1} g^k / k * T_k(t)
    // h = 4 (power of two), m = 4.75. Signs sigma_k (period 4: +,+,-,-) folded in.
    const double a = 0.75, bnd = 8.75;
    const double m = 0.5 * (a + bnd), h = 0.5 * (bnd - a);
    const double alpha = h / m;
    const double gam = (1.0 - sqrt(1.0 - alpha * alpha)) / alpha;

    Coeffs co;
    co.c[0] = (float)log(h / (2.0 * gam));
    double g = 1.0;
    for (int k = 1; k <= NDEG; ++k) {
        g *= gam;
        const double ck  = (((k & 1) ? 2.0 : -2.0) * g) / (double)k;
        const double sig = ((k >> 1) & 1) ? -1.0 : 1.0;
        co.c[k] = (float)(ck * sig);
    }

    const int B = in_sizes[0] / (NDIM * NDIM);
    spd_log_mfma<<<B, 256, 0, stream>>>(d_in[0], (float*)d_out, co);
}

// Round 10
// 219.166 us; speedup vs baseline: 2.7272x; 1.0809x over previous
//
#include <hip/hip_runtime.h>
#include <hip/hip_bf16.h>
#include <cmath>

#define NDIM  64
#define PSTR  72        // LDS plane row stride in f16 (144 B, 16B-aligned rows)
#define NDEG  13        // Chebyshev degree for log on [0.75, 8.75]; trunc err ~7e-5,
                        // 57x below the measured f16 error floor (absmax 3.9e-3, r5-r9)
#define TRI   2080      // 64*65/2
#define CMID  4.75f     // interval midpoint m; h = 4

struct Coeffs {
    float c[NDEG + 1];  // c'_k = sigma_k * c_k  (sigma = +,+,-,-,+,+,...)
};

typedef _Float16 f16x8 __attribute__((ext_vector_type(8)));
typedef _Float16 f16x4 __attribute__((ext_vector_type(4)));
typedef float    f32x4 __attribute__((ext_vector_type(4)));

// SPD => symmetric under the TRUE dtype; wrong reinterpretation gives O(1)/NaN residual.
__device__ __forceinline__ bool sniff_is_bf16(const void* xin)
{
    const float*          f0 = (const float*)xin;
    const unsigned short* h0 = (const unsigned short*)xin;
    const int pi[8] = {1, 3, 5, 2, 4, 6, 7, 8};
    const int pj[8] = {2, 7, 11, 9, 13, 17, 23, 31};
    float fsym = 0.f, bsym = 0.f;
    #pragma unroll
    for (int p = 0; p < 8; ++p) {
        const int i = pi[p], j = pj[p];
        fsym += fabsf(f0[i * NDIM + j] - f0[j * NDIM + i]);
        union { unsigned u; float f; } ua, ub;
        ua.u = ((unsigned)h0[i * NDIM + j]) << 16;
        ub.u = ((unsigned)h0[j * NDIM + i]) << 16;
        bsym += fabsf(ua.f - ub.f);
    }
    if (fsym != fsym) return true;
    if (bsym != bsym) return false;
    return bsym < fsym;
}

// One 64x64 matrix per 256-thread block (4 waves). COLUMN-STRIP decomposition:
// wave w owns cols n0 = 16w..16w+15, ALL 64 rows, as 4 stacked 16x16 C/D tiles.
// T_{k+1}[:,strip] = A2*T_k[:,strip] - T_{k-1}[:,strip] is closed per wave ->
// ZERO barriers in the recurrence loop; B-operands rebuilt from the wave's OWN
// C/D registers through a wave-private LDS scratch.
//
// Latency scheme (r9-verified, 99.4us @ NDEG 19): no manual lgkmcnt(0) drain --
// DS ops from one wave execute in order; compiler emits counted waits.
// Interleave w0,w1 -> r0 -> w2,w3 -> r1 so r1 latency hides under the first 4
// MFMAs. setprio(1) around the MFMA cluster (barrier-free/desynced waves:
// attn-like regime where setprio measured +4-7%).
//
// Round-10 change: NDEG 19 -> 13. All pipes sat at 35-50% (MfmaUtil 34.7,
// VALUBusy 49.3, LDS ~30%) with no dominant stall -> throughput-bound on the
// mix; cut work uniformly. Truncation tail (2/(N+1)) g^(N+1)/(1-g), g=0.547:
// 1.3e-6 @19 -> 6.8e-5 @13, still 57x below the 3.9e-3 f16 floor. Eigenvalues
// of AA^T/64 + I lie in [1,~5.5] inside the [0.75,8.75] interval.
//
// Sign algebra (HW-verified r6/r7): V_k = sigma_k T_k (sigma period 4: +,+,-,-),
// every step is one in-place set = mfma(A2, frag, set) with C-in = V_{k-2},
// frag = f16((k even ? - : +) V_{k-1}); c'_k = sigma_k c_k host-folded.
// A2 = (X-mI)/2 and T1 = A2/2 are EXACT in f16 for bf16 input.
//
// Register budget (r6 lesson): launch_bounds(256,2) -> 256-reg cap; measured
// r7/r9: VGPR 56-60, no spill, clean HBM traffic.
// Scratch discipline (rule #20): named state, literal subscripts only.

#define XCHG_STEP(S0, S1, S2, S3, D0, D1, D2, D3, CK, SGN)                        \
    {                                                                             \
        f16x4 w0_, w1_, w2_, w3_;                                                 \
        w0_[0]=(_Float16)(SGN S0[0]); w0_[1]=(_Float16)(SGN S0[1]);               \
        w0_[2]=(_Float16)(SGN S0[2]); w0_[3]=(_Float16)(SGN S0[3]);               \
        w1_[0]=(_Float16)(SGN S1[0]); w1_[1]=(_Float16)(SGN S1[1]);               \
        w1_[2]=(_Float16)(SGN S1[2]); w1_[3]=(_Float16)(SGN S1[3]);               \
        *(f16x4*)&p1[wa0] = w0_;  *(f16x4*)&p1[wa1] = w1_;                        \
        const f16x8 bf0_ = *(const f16x8*)&p1[ra0];    /* after wa0,wa1: in-order DS */ \
        w2_[0]=(_Float16)(SGN S2[0]); w2_[1]=(_Float16)(SGN S2[1]);               \
        w2_[2]=(_Float16)(SGN S2[2]); w2_[3]=(_Float16)(SGN S2[3]);               \
        w3_[0]=(_Float16)(SGN S3[0]); w3_[1]=(_Float16)(SGN S3[1]);               \
        w3_[2]=(_Float16)(SGN S3[2]); w3_[3]=(_Float16)(SGN S3[3]);               \
        *(f16x4*)&p1[wa2] = w2_;  *(f16x4*)&p1[wa3] = w3_;                        \
        const f16x8 bf1_ = *(const f16x8*)&p1[ra1];    /* after wa2,wa3 */        \
        __builtin_amdgcn_s_setprio(1);                                            \
        D0 = __builtin_amdgcn_mfma_f32_16x16x32_f16(a00, bf0_, D0, 0, 0, 0);      \
        D1 = __builtin_amdgcn_mfma_f32_16x16x32_f16(a10, bf0_, D1, 0, 0, 0);      \
        D2 = __builtin_amdgcn_mfma_f32_16x16x32_f16(a20, bf0_, D2, 0, 0, 0);      \
        D3 = __builtin_amdgcn_mfma_f32_16x16x32_f16(a30, bf0_, D3, 0, 0, 0);      \
        D0 = __builtin_amdgcn_mfma_f32_16x16x32_f16(a01, bf1_, D0, 0, 0, 0);      \
        D1 = __builtin_amdgcn_mfma_f32_16x16x32_f16(a11, bf1_, D1, 0, 0, 0);      \
        D2 = __builtin_amdgcn_mfma_f32_16x16x32_f16(a21, bf1_, D2, 0, 0, 0);      \
        D3 = __builtin_amdgcn_mfma_f32_16x16x32_f16(a31, bf1_, D3, 0, 0, 0);      \
        __builtin_amdgcn_s_setprio(0);                                            \
        const float ck_ = (CK);                                                   \
        y0 += ck_ * D0; y1 += ck_ * D1; y2 += ck_ * D2; y3 += ck_ * D3;           \
    }

#define TRIW1(Y, R, MR, NC)                                                      \
    { const int m_ = (MR) + (R);                                                 \
      if (m_ <= (NC)) ybuf[m_ * NDIM - (m_ * (m_ - 1)) / 2 + ((NC) - m_)] = Y[R]; }
#define TRIW(Y, MR, NC) \
    TRIW1(Y, 0, MR, NC) TRIW1(Y, 1, MR, NC) TRIW1(Y, 2, MR, NC) TRIW1(Y, 3, MR, NC)

__global__ __launch_bounds__(256, 2)
void spd_log_mfma(const void* __restrict__ xin,
                  float* __restrict__ out,
                  Coeffs co)
{
    __shared__ __align__(16) _Float16 planes[2][NDIM * PSTR];   // 2 x 9216 B

    const int b    = blockIdx.x;
    const int tid  = threadIdx.x;
    const int wave = tid >> 6;
    const int lane = tid & 63;
    const int l    = lane & 15;
    const int q    = lane >> 4;
    const int n0   = wave * 16;      // strip base column

    _Float16* const p0 = &planes[0][0];
    _Float16* const p1 = &planes[1][0];

    const bool isb = sniff_is_bf16(xin);

    // ---------------- stage: p0 = A2 = (X-mI)/2 (EXACT f16 for bf16 input) ----------------
    if (isb) {
        const uint2* xv = (const uint2*)((const unsigned short*)xin + (size_t)b * (NDIM * NDIM));
        #pragma unroll
        for (int r = 0; r < 4; ++r) {
            const int e4 = tid + r * 256;          // 1024 quads
            const int e0 = e4 * 4;
            const int row = e0 >> 6, col = e0 & 63;
            const uint2 w = xv[e4];
            union { unsigned u; float f; } u0, u1, u2, u3;
            u0.u = (w.x & 0xffffu) << 16; u1.u = (w.x & 0xffff0000u);
            u2.u = (w.y & 0xffffu) << 16; u3.u = (w.y & 0xffff0000u);
            const float v0 = u0.f - ((col + 0 == row) ? CMID : 0.f);
            const float v1 = u1.f - ((col + 1 == row) ? CMID : 0.f);
            const float v2 = u2.f - ((col + 2 == row) ? CMID : 0.f);
            const float v3 = u3.f - ((col + 3 == row) ? CMID : 0.f);
            f16x4 h0;
            h0[0] = (_Float16)(v0 * 0.5f); h0[1] = (_Float16)(v1 * 0.5f);
            h0[2] = (_Float16)(v2 * 0.5f); h0[3] = (_Float16)(v3 * 0.5f);
            *(f16x4*)&p0[row * PSTR + col] = h0;
        }
    } else {
        const float4* xv = (const float4*)((const float*)xin + (size_t)b * (NDIM * NDIM));
        #pragma unroll
        for (int r = 0; r < 4; ++r) {
            const int e4 = tid + r * 256;
            const int e0 = e4 * 4;
            const int row = e0 >> 6, col = e0 & 63;
            const float4 w = xv[e4];
            const float v0 = w.x - ((col + 0 == row) ? CMID : 0.f);
            const float v1 = w.y - ((col + 1 == row) ? CMID : 0.f);
            const float v2 = w.z - ((col + 2 == row) ? CMID : 0.f);
            const float v3 = w.w - ((col + 3 == row) ? CMID : 0.f);
            f16x4 h0;
            h0[0] = (_Float16)(v0 * 0.5f); h0[1] = (_Float16)(v1 * 0.5f);
            h0[2] = (_Float16)(v2 * 0.5f); h0[3] = (_Float16)(v3 * 0.5f);
            *(f16x4*)&p0[row * PSTR + col] = h0;
        }
    }
    __syncthreads();

    // ---------------- A-fragments: a{mt}{kt} = A2[16mt+l][32kt+8q+i], fixed ----------------
    const int ar = l * PSTR + 8 * q;
    const f16x8 a00 = *(const f16x8*)&p0[ar                 ];
    const f16x8 a01 = *(const f16x8*)&p0[ar + 32            ];
    const f16x8 a10 = *(const f16x8*)&p0[ar + 16 * PSTR     ];
    const f16x8 a11 = *(const f16x8*)&p0[ar + 16 * PSTR + 32];
    const f16x8 a20 = *(const f16x8*)&p0[ar + 32 * PSTR     ];
    const f16x8 a21 = *(const f16x8*)&p0[ar + 32 * PSTR + 32];
    const f16x8 a30 = *(const f16x8*)&p0[ar + 48 * PSTR     ];
    const f16x8 a31 = *(const f16x8*)&p0[ar + 48 * PSTR + 32];

    // ---------------- init C/D state: sa = V0 = I, sb = V1 = T1 = A2/2 ----------------
    // Tile mt element (row 16mt+4q+r, col n0+l); T1[row][col] read via A2 symmetry.
    const int nc  = n0 + l;
    const float cc0 = co.c[0], cc1 = co.c[1];
    f32x4 sa0, sa1, sa2, sa3;
    f32x4 sb0, sb1, sb2, sb3;
    f32x4 y0, y1, y2, y3;

#define INIT_TILE(SB, SA, Y, MT)                                                 \
    {                                                                            \
        const f16x4 tv = *(const f16x4*)&p0[nc * PSTR + 16 * (MT) + 4 * q];      \
        const float t0_ = 0.5f * (float)tv[0], t1_ = 0.5f * (float)tv[1];        \
        const float t2_ = 0.5f * (float)tv[2], t3_ = 0.5f * (float)tv[3];        \
        SB[0] = t0_; SB[1] = t1_; SB[2] = t2_; SB[3] = t3_;                      \
        const float d0_ = (16 * (MT) + 4 * q + 0 == nc) ? 1.f : 0.f;             \
        const float d1_ = (16 * (MT) + 4 * q + 1 == nc) ? 1.f : 0.f;             \
        const float d2_ = (16 * (MT) + 4 * q + 2 == nc) ? 1.f : 0.f;             \
        const float d3_ = (16 * (MT) + 4 * q + 3 == nc) ? 1.f : 0.f;             \
        SA[0] = d0_; SA[1] = d1_; SA[2] = d2_; SA[3] = d3_;                      \
        Y[0] = cc1 * t0_ + cc0 * d0_; Y[1] = cc1 * t1_ + cc0 * d1_;              \
        Y[2] = cc1 * t2_ + cc0 * d2_; Y[3] = cc1 * t3_ + cc0 * d3_;              \
    }
    INIT_TILE(sb0, sa0, y0, 0)
    INIT_TILE(sb1, sa1, y1, 1)
    INIT_TILE(sb2, sa2, y2, 2)
    INIT_TILE(sb3, sa3, y3, 3)
#undef INIT_TILE
    __syncthreads();   // all waves done reading p0 before anyone reuses it (ybuf)

    // ---------------- scratch offsets (f16 units, loop-invariant) ----------------
    const int sw  = wave * 1024;
    const int qh  = q >> 1, qlo = q & 1;
    const int wa0 = sw +   0 + qh * 128 + ((l ^ (    2 * qh)) << 3) + (qlo << 2);
    const int wa1 = sw + 256 + qh * 128 + ((l ^ (4 + 2 * qh)) << 3) + (qlo << 2);
    const int wa2 = sw + 512 + qh * 128 + ((l ^ (    2 * qh)) << 3) + (qlo << 2);
    const int wa3 = sw + 768 + qh * 128 + ((l ^ (4 + 2 * qh)) << 3) + (qlo << 2);
    const int ra0 = sw + (    qh) * 256 + qlo * 128 + ((l ^ (2 * q)) << 3);
    const int ra1 = sw + (2 + qh) * 256 + qlo * 128 + ((l ^ (2 * q)) << 3);

    // ---------------- Chebyshev recurrence: 12 steps (k=2..13), ZERO barriers ----------------
    // even k: frag = f16(-sb) = sigma_k*T_{k-1}, D=sa (C-in = V_{k-2}); odd: frag = +f16(sa).
    for (int kk = 2; kk < NDEG; kk += 2) {
        XCHG_STEP(sb0, sb1, sb2, sb3, sa0, sa1, sa2, sa3, co.c[kk],     -)
        XCHG_STEP(sa0, sa1, sa2, sa3, sb0, sb1, sb2, sb3, co.c[kk + 1], +)
    }

    // ---------------- output: stage triu in LDS (p0 region), coalesced stores ----------------
    float* ybuf = (float*)p0;      // 8320 B <= 9216 B
    TRIW(y0,      4 * q, nc)
    TRIW(y1, 16 + 4 * q, nc)
    TRIW(y2, 32 + 4 * q, nc)
    TRIW(y3, 48 + 4 * q, nc)
    __syncthreads();

    float4* dst = (float4*)(out + (size_t)b * TRI);
    const float4* src = (const float4*)ybuf;
    for (int e = tid; e < TRI / 4; e += 256)
        dst[e] = src[e];
}

extern "C" void kernel_launch(void* const* d_in, const int* in_sizes, int n_in,
                              void* d_out, int out_size, void* d_ws, size_t ws_size,
                              hipStream_t stream)
{
    (void)n_in; (void)d_ws; (void)ws_size; (void)out_size;

    // Chebyshev coefficients of log on [a,b] = [0.75, 8.75]:
    // log(m + h t) = log(h/(2g)) + sum_{k>=1} 2(-1)^{k+1} g^k / k * T_k(t)
    // h = 4 (power of two), m = 4.75. Signs sigma_k (period 4: +,+,-,-) folded in.
    const double a = 0.75, bnd = 8.75;
    const double m = 0.5 * (a + bnd), h = 0.5 * (bnd - a);
    const double alpha = h / m;
    const double gam = (1.0 - sqrt(1.0 - alpha * alpha)) / alpha;

    Coeffs co;
    co.c[0] = (float)log(h / (2.0 * gam));
    double g = 1.0;
    for (int k = 1; k <= NDEG; ++k) {
        g *= gam;
        const double ck  = (((k & 1) ? 2.0 : -2.0) * g) / (double)k;
        const double sig = ((k >> 1) & 1) ? -1.0 : 1.0;
        co.c[k] = (float)(ck * sig);
    }

    const int B = in_sizes[0] / (NDIM * NDIM);
    spd_log_mfma<<<B, 256, 0, stream>>>(d_in[0], (float*)d_out, co);
}

// Round 11
// 212.675 us; speedup vs baseline: 2.8104x; 1.0305x over previous
//
#include <hip/hip_runtime.h>
#include <hip/hip_bf16.h>
#include <cmath>

#define NDIM  64
#define PSTR  72        // LDS plane row stride in f16 (144 B, 16B-aligned rows)
#define NDEG  11        // Chebyshev degree for log on [0.75, 8.75]; trunc err ~2.7e-4,
                        // 15x below the measured f16 error floor (absmax 3.9e-3, r5-r10;
                        // r10 A/B: 19->13 changed absmax by ZERO -- floor dominates)
#define TRI   2080      // 64*65/2
#define CMID  4.75f     // interval midpoint m; h = 4

struct Coeffs {
    float c[NDEG + 1];  // c'_k = sigma_k * c_k  (sigma = +,+,-,-,+,+,...)
};

typedef _Float16 f16x8 __attribute__((ext_vector_type(8)));
typedef _Float16 f16x4 __attribute__((ext_vector_type(4)));
typedef float    f32x4 __attribute__((ext_vector_type(4)));

// SPD => symmetric under the TRUE dtype; wrong reinterpretation gives O(1)/NaN residual.
__device__ __forceinline__ bool sniff_is_bf16(const void* xin)
{
    const float*          f0 = (const float*)xin;
    const unsigned short* h0 = (const unsigned short*)xin;
    const int pi[8] = {1, 3, 5, 2, 4, 6, 7, 8};
    const int pj[8] = {2, 7, 11, 9, 13, 17, 23, 31};
    float fsym = 0.f, bsym = 0.f;
    #pragma unroll
    for (int p = 0; p < 8; ++p) {
        const int i = pi[p], j = pj[p];
        fsym += fabsf(f0[i * NDIM + j] - f0[j * NDIM + i]);
        union { unsigned u; float f; } ua, ub;
        ua.u = ((unsigned)h0[i * NDIM + j]) << 16;
        ub.u = ((unsigned)h0[j * NDIM + i]) << 16;
        bsym += fabsf(ua.f - ub.f);
    }
    if (fsym != fsym) return true;
    if (bsym != bsym) return false;
    return bsym < fsym;
}

// One 64x64 matrix per 256-thread block (4 waves). COLUMN-STRIP decomposition:
// wave w owns cols n0 = 16w..16w+15, ALL 64 rows, as 4 stacked 16x16 C/D tiles.
// T_{k+1}[:,strip] = A2*T_k[:,strip] - T_{k-1}[:,strip] is closed per wave ->
// ZERO barriers in the recurrence loop; B-operands rebuilt from the wave's OWN
// C/D registers through a wave-private LDS scratch.
//
// Latency scheme (r9-verified): no manual lgkmcnt(0) drain -- DS ops from one
// wave execute in order; compiler emits counted waits. Interleave
// w0,w1 -> r0 -> w2,w3 -> r1 so r1 latency hides under the first 4 MFMAs.
// setprio(1) around the MFMA cluster (barrier-free/desynced waves).
//
// Round-11 changes (r10 budget: steps 3.15us each, fixed ~43us):
//  (a) NDEG 13 -> 11: -2 steps. r10 A/B proved truncation (1.3e-6 vs 6.8e-5)
//      is invisible vs the f16 floor; 2.7e-4 @ 11 keeps 15x margin.
//  (b) bf16 staging via 2x uint4 (16B) loads + 2x ds_write_b128 (was 4x uint2
//      + 4x b64): halves VMEM/DS instruction count in the fixed phase.
//
// Sign algebra (HW-verified r6/r7): V_k = sigma_k T_k (sigma period 4: +,+,-,-),
// every step is one in-place set = mfma(A2, frag, set) with C-in = V_{k-2},
// frag = f16((k even ? - : +) V_{k-1}); c'_k = sigma_k c_k host-folded.
// A2 = (X-mI)/2 and T1 = A2/2 are EXACT in f16 for bf16 input.
//
// Register budget (r6 lesson): launch_bounds(256,2) -> 256-reg cap; measured
// r7-r10: VGPR 56-60, no spill, clean HBM traffic.
// Scratch discipline (rule #20): named state, literal subscripts only.

#define XCHG_STEP(S0, S1, S2, S3, D0, D1, D2, D3, CK, SGN)                        \
    {                                                                             \
        f16x4 w0_, w1_, w2_, w3_;                                                 \
        w0_[0]=(_Float16)(SGN S0[0]); w0_[1]=(_Float16)(SGN S0[1]);               \
        w0_[2]=(_Float16)(SGN S0[2]); w0_[3]=(_Float16)(SGN S0[3]);               \
        w1_[0]=(_Float16)(SGN S1[0]); w1_[1]=(_Float16)(SGN S1[1]);               \
        w1_[2]=(_Float16)(SGN S1[2]); w1_[3]=(_Float16)(SGN S1[3]);               \
        *(f16x4*)&p1[wa0] = w0_;  *(f16x4*)&p1[wa1] = w1_;                        \
        const f16x8 bf0_ = *(const f16x8*)&p1[ra0];    /* after wa0,wa1: in-order DS */ \
        w2_[0]=(_Float16)(SGN S2[0]); w2_[1]=(_Float16)(SGN S2[1]);               \
        w2_[2]=(_Float16)(SGN S2[2]); w2_[3]=(_Float16)(SGN S2[3]);               \
        w3_[0]=(_Float16)(SGN S3[0]); w3_[1]=(_Float16)(SGN S3[1]);               \
        w3_[2]=(_Float16)(SGN S3[2]); w3_[3]=(_Float16)(SGN S3[3]);               \
        *(f16x4*)&p1[wa2] = w2_;  *(f16x4*)&p1[wa3] = w3_;                        \
        const f16x8 bf1_ = *(const f16x8*)&p1[ra1];    /* after wa2,wa3 */        \
        __builtin_amdgcn_s_setprio(1);                                            \
        D0 = __builtin_amdgcn_mfma_f32_16x16x32_f16(a00, bf0_, D0, 0, 0, 0);      \
        D1 = __builtin_amdgcn_mfma_f32_16x16x32_f16(a10, bf0_, D1, 0, 0, 0);      \
        D2 = __builtin_amdgcn_mfma_f32_16x16x32_f16(a20, bf0_, D2, 0, 0, 0);      \
        D3 = __builtin_amdgcn_mfma_f32_16x16x32_f16(a30, bf0_, D3, 0, 0, 0);      \
        D0 = __builtin_amdgcn_mfma_f32_16x16x32_f16(a01, bf1_, D0, 0, 0, 0);      \
        D1 = __builtin_amdgcn_mfma_f32_16x16x32_f16(a11, bf1_, D1, 0, 0, 0);      \
        D2 = __builtin_amdgcn_mfma_f32_16x16x32_f16(a21, bf1_, D2, 0, 0, 0);      \
        D3 = __builtin_amdgcn_mfma_f32_16x16x32_f16(a31, bf1_, D3, 0, 0, 0);      \
        __builtin_amdgcn_s_setprio(0);                                            \
        const float ck_ = (CK);                                                   \
        y0 += ck_ * D0; y1 += ck_ * D1; y2 += ck_ * D2; y3 += ck_ * D3;           \
    }

#define TRIW1(Y, R, MR, NC)                                                      \
    { const int m_ = (MR) + (R);                                                 \
      if (m_ <= (NC)) ybuf[m_ * NDIM - (m_ * (m_ - 1)) / 2 + ((NC) - m_)] = Y[R]; }
#define TRIW(Y, MR, NC) \
    TRIW1(Y, 0, MR, NC) TRIW1(Y, 1, MR, NC) TRIW1(Y, 2, MR, NC) TRIW1(Y, 3, MR, NC)

__global__ __launch_bounds__(256, 2)
void spd_log_mfma(const void* __restrict__ xin,
                  float* __restrict__ out,
                  Coeffs co)
{
    __shared__ __align__(16) _Float16 planes[2][NDIM * PSTR];   // 2 x 9216 B

    const int b    = blockIdx.x;
    const int tid  = threadIdx.x;
    const int wave = tid >> 6;
    const int lane = tid & 63;
    const int l    = lane & 15;
    const int q    = lane >> 4;
    const int n0   = wave * 16;      // strip base column

    _Float16* const p0 = &planes[0][0];
    _Float16* const p1 = &planes[1][0];

    const bool isb = sniff_is_bf16(xin);

    // ---------------- stage: p0 = A2 = (X-mI)/2 (EXACT f16 for bf16 input) ----------------
    if (isb) {
        const uint4* xv = (const uint4*)((const unsigned short*)xin + (size_t)b * (NDIM * NDIM));
        #pragma unroll
        for (int r = 0; r < 2; ++r) {
            const int e8 = tid + r * 256;          // 512 octets of 8 bf16
            const int e0 = e8 * 8;
            const int row = e0 >> 6, col = e0 & 63;  // col multiple of 8
            const uint4 w = xv[e8];
            union { unsigned u; float f; } u0, u1, u2, u3, u4, u5, u6, u7;
            u0.u = (w.x & 0xffffu) << 16; u1.u = (w.x & 0xffff0000u);
            u2.u = (w.y & 0xffffu) << 16; u3.u = (w.y & 0xffff0000u);
            u4.u = (w.z & 0xffffu) << 16; u5.u = (w.z & 0xffff0000u);
            u6.u = (w.w & 0xffffu) << 16; u7.u = (w.w & 0xffff0000u);
            const float v0 = u0.f - ((col + 0 == row) ? CMID : 0.f);
            const float v1 = u1.f - ((col + 1 == row) ? CMID : 0.f);
            const float v2 = u2.f - ((col + 2 == row) ? CMID : 0.f);
            const float v3 = u3.f - ((col + 3 == row) ? CMID : 0.f);
            const float v4 = u4.f - ((col + 4 == row) ? CMID : 0.f);
            const float v5 = u5.f - ((col + 5 == row) ? CMID : 0.f);
            const float v6 = u6.f - ((col + 6 == row) ? CMID : 0.f);
            const float v7 = u7.f - ((col + 7 == row) ? CMID : 0.f);
            f16x8 h;
            h[0] = (_Float16)(v0 * 0.5f); h[1] = (_Float16)(v1 * 0.5f);
            h[2] = (_Float16)(v2 * 0.5f); h[3] = (_Float16)(v3 * 0.5f);
            h[4] = (_Float16)(v4 * 0.5f); h[5] = (_Float16)(v5 * 0.5f);
            h[6] = (_Float16)(v6 * 0.5f); h[7] = (_Float16)(v7 * 0.5f);
            *(f16x8*)&p0[row * PSTR + col] = h;     // 16B aligned (col%8==0, PSTR*2%16==0... row*144+2col ≡ 0 mod 16)
        }
    } else {
        const float4* xv = (const float4*)((const float*)xin + (size_t)b * (NDIM * NDIM));
        #pragma unroll
        for (int r = 0; r < 4; ++r) {
            const int e4 = tid + r * 256;
            const int e0 = e4 * 4;
            const int row = e0 >> 6, col = e0 & 63;
            const float4 w = xv[e4];
            const float v0 = w.x - ((col + 0 == row) ? CMID : 0.f);
            const float v1 = w.y - ((col + 1 == row) ? CMID : 0.f);
            const float v2 = w.z - ((col + 2 == row) ? CMID : 0.f);
            const float v3 = w.w - ((col + 3 == row) ? CMID : 0.f);
            f16x4 h0;
            h0[0] = (_Float16)(v0 * 0.5f); h0[1] = (_Float16)(v1 * 0.5f);
            h0[2] = (_Float16)(v2 * 0.5f); h0[3] = (_Float16)(v3 * 0.5f);
            *(f16x4*)&p0[row * PSTR + col] = h0;
        }
    }
    __syncthreads();

    // ---------------- A-fragments: a{mt}{kt} = A2[16mt+l][32kt+8q+i], fixed ----------------
    const int ar = l * PSTR + 8 * q;
    const f16x8 a00 = *(const f16x8*)&p0[ar                 ];
    const f16x8 a01 = *(const f16x8*)&p0[ar + 32            ];
    const f16x8 a10 = *(const f16x8*)&p0[ar + 16 * PSTR     ];
    const f16x8 a11 = *(const f16x8*)&p0[ar + 16 * PSTR + 32];
    const f16x8 a20 = *(const f16x8*)&p0[ar + 32 * PSTR     ];
    const f16x8 a21 = *(const f16x8*)&p0[ar + 32 * PSTR + 32];
    const f16x8 a30 = *(const f16x8*)&p0[ar + 48 * PSTR     ];
    const f16x8 a31 = *(const f16x8*)&p0[ar + 48 * PSTR + 32];

    // ---------------- init C/D state: sa = V0 = I, sb = V1 = T1 = A2/2 ----------------
    // Tile mt element (row 16mt+4q+r, col n0+l); T1[row][col] read via A2 symmetry.
    const int nc  = n0 + l;
    const float cc0 = co.c[0], cc1 = co.c[1];
    f32x4 sa0, sa1, sa2, sa3;
    f32x4 sb0, sb1, sb2, sb3;
    f32x4 y0, y1, y2, y3;

#define INIT_TILE(SB, SA, Y, MT)                                                 \
    {                                                                            \
        const f16x4 tv = *(const f16x4*)&p0[nc * PSTR + 16 * (MT) + 4 * q];      \
        const float t0_ = 0.5f * (float)tv[0], t1_ = 0.5f * (float)tv[1];        \
        const float t2_ = 0.5f * (float)tv[2], t3_ = 0.5f * (float)tv[3];        \
        SB[0] = t0_; SB[1] = t1_; SB[2] = t2_; SB[3] = t3_;                      \
        const float d0_ = (16 * (MT) + 4 * q + 0 == nc) ? 1.f : 0.f;             \
        const float d1_ = (16 * (MT) + 4 * q + 1 == nc) ? 1.f : 0.f;             \
        const float d2_ = (16 * (MT) + 4 * q + 2 == nc) ? 1.f : 0.f;             \
        const float d3_ = (16 * (MT) + 4 * q + 3 == nc) ? 1.f : 0.f;             \
        SA[0] = d0_; SA[1] = d1_; SA[2] = d2_; SA[3] = d3_;                      \
        Y[0] = cc1 * t0_ + cc0 * d0_; Y[1] = cc1 * t1_ + cc0 * d1_;              \
        Y[2] = cc1 * t2_ + cc0 * d2_; Y[3] = cc1 * t3_ + cc0 * d3_;              \
    }
    INIT_TILE(sb0, sa0, y0, 0)
    INIT_TILE(sb1, sa1, y1, 1)
    INIT_TILE(sb2, sa2, y2, 2)
    INIT_TILE(sb3, sa3, y3, 3)
#undef INIT_TILE
    __syncthreads();   // all waves done reading p0 before anyone reuses it (ybuf)

    // ---------------- scratch offsets (f16 units, loop-invariant) ----------------
    const int sw  = wave * 1024;
    const int qh  = q >> 1, qlo = q & 1;
    const int wa0 = sw +   0 + qh * 128 + ((l ^ (    2 * qh)) << 3) + (qlo << 2);
    const int wa1 = sw + 256 + qh * 128 + ((l ^ (4 + 2 * qh)) << 3) + (qlo << 2);
    const int wa2 = sw + 512 + qh * 128 + ((l ^ (    2 * qh)) << 3) + (qlo << 2);
    const int wa3 = sw + 768 + qh * 128 + ((l ^ (4 + 2 * qh)) << 3) + (qlo << 2);
    const int ra0 = sw + (    qh) * 256 + qlo * 128 + ((l ^ (2 * q)) << 3);
    const int ra1 = sw + (2 + qh) * 256 + qlo * 128 + ((l ^ (2 * q)) << 3);

    // ---------------- Chebyshev recurrence: 10 steps (k=2..11), ZERO barriers ----------------
    // even k: frag = f16(-sb) = sigma_k*T_{k-1}, D=sa (C-in = V_{k-2}); odd: frag = +f16(sa).
    for (int kk = 2; kk < NDEG; kk += 2) {
        XCHG_STEP(sb0, sb1, sb2, sb3, sa0, sa1, sa2, sa3, co.c[kk],     -)
        XCHG_STEP(sa0, sa1, sa2, sa3, sb0, sb1, sb2, sb3, co.c[kk + 1], +)
    }

    // ---------------- output: stage triu in LDS (p0 region), coalesced stores ----------------
    float* ybuf = (float*)p0;      // 8320 B <= 9216 B
    TRIW(y0,      4 * q, nc)
    TRIW(y1, 16 + 4 * q, nc)
    TRIW(y2, 32 + 4 * q, nc)
    TRIW(y3, 48 + 4 * q, nc)
    __syncthreads();

    float4* dst = (float4*)(out + (size_t)b * TRI);
    const float4* src = (const float4*)ybuf;
    for (int e = tid; e < TRI / 4; e += 256)
        dst[e] = src[e];
}

extern "C" void kernel_launch(void* const* d_in, const int* in_sizes, int n_in,
                              void* d_out, int out_size, void* d_ws, size_t ws_size,
                              hipStream_t stream)
{
    (void)n_in; (void)d_ws; (void)ws_size; (void)out_size;

    // Chebyshev coefficients of log on [a,b] = [0.75, 8.75]:
    // log(m + h t) = log(h/(2g)) + sum_{k>=1} 2(-1)^{k+1} g^k / k * T_k(t)
    // h = 4 (power of two), m = 4.75. Signs sigma_k (period 4: +,+,-,-) folded in.
    const double a = 0.75, bnd = 8.75;
    const double m = 0.5 * (a + bnd), h = 0.5 * (bnd - a);
    const double alpha = h / m;
    const double gam = (1.0 - sqrt(1.0 - alpha * alpha)) / alpha;

    Coeffs co;
    co.c[0] = (float)log(h / (2.0 * gam));
    double g = 1.0;
    for (int k = 1; k <= NDEG; ++k) {
        g *= gam;
        const double ck  = (((k & 1) ? 2.0 : -2.0) * g) / (double)k;
        const double sig = ((k >> 1) & 1) ? -1.0 : 1.0;
        co.c[k] = (float)(ck * sig);
    }

    const int B = in_sizes[0] / (NDIM * NDIM);
    spd_log_mfma<<<B, 256, 0, stream>>>(d_in[0], (float*)d_out, co);
}